// Round 3
// baseline (2655.777 us; speedup 1.0000x reference)
//
#include <hip/hip_runtime.h>

#define TT 256
#define BATCH 2048
#define DATA 32
#define WSLOTS 52

typedef __bf16 bf16x8 __attribute__((ext_vector_type(8)));
typedef float f32x4 __attribute__((ext_vector_type(4)));

__device__ __forceinline__ unsigned short f2bf(float f) {
    union { float f; unsigned u; } v; v.f = f;
    return (unsigned short)((v.u + 0x7FFFu + ((v.u >> 16) & 1u)) >> 16);  // RN
}
__device__ __forceinline__ float bflo(unsigned u) {
    union { unsigned u; float f; } v; v.u = u << 16; return v.f;
}
__device__ __forceinline__ float bfhi(unsigned u) {
    union { unsigned u; float f; } v; v.u = u & 0xffff0000u; return v.f;
}

// global fp32 x8 -> bf16x8 fragment
__device__ __forceinline__ bf16x8 ldw8(const float* __restrict__ p) {
    float4 a = *(const float4*)p;
    float4 b = *(const float4*)(p + 4);
    union { bf16x8 v; unsigned short s[8]; } u;
    u.s[0] = f2bf(a.x); u.s[1] = f2bf(a.y); u.s[2] = f2bf(a.z); u.s[3] = f2bf(a.w);
    u.s[4] = f2bf(b.x); u.s[5] = f2bf(b.y); u.s[6] = f2bf(b.z); u.s[7] = f2bf(b.w);
    return u.v;
}

// swizzled LDS fragment read: 256-B row stride, 16-B slot XOR (row&7)
__device__ __forceinline__ bf16x8 ldx(const char* base, int row, int kbyte) {
    return *(const bf16x8*)(base + row * 256 + (kbyte ^ ((row & 7) << 4)));
}

// Hidden layer: 8 output tiles, KC k-chunks. GETW = A-frag (weights), xf = B-frag
// (batch rows). D: lane&15 = batch row m, (lane>>4)*4+j = out col -> 4 consecutive
// cols per lane -> one b64 store per tile.
#define HID_LAYER(GETW, KC, SRC, DST, BOFF)                                          \
    {                                                                                \
        bf16x8 xf[4];                                                                \
        _Pragma("unroll") for (int kc = 0; kc < (KC); ++kc)                          \
            xf[kc] = ldx(SRC, r8, kc * 64 + g * 16);                                 \
        _Pragma("unroll") for (int nt = 0; nt < 8; ++nt) {                           \
            f32x4 acc = *(const f32x4*)(biasb + (BOFF) + nt * 16 + g * 4);           \
            _Pragma("unroll") for (int kc = 0; kc < (KC); ++kc)                      \
                acc = __builtin_amdgcn_mfma_f32_16x16x32_bf16(GETW, xf[kc], acc, 0, 0, 0); \
            union { uint2 u; unsigned short s[4]; } p;                               \
            p.s[0] = f2bf(fmaxf(acc[0], 0.f)); p.s[1] = f2bf(fmaxf(acc[1], 0.f));    \
            p.s[2] = f2bf(fmaxf(acc[2], 0.f)); p.s[3] = f2bf(fmaxf(acc[3], 0.f));    \
            *(uint2*)((DST) + m * 256 + ((nt * 32 + g * 8) ^ ((m & 7) << 4))) = p.u; \
        }                                                                            \
    }

// One RK stage: assemble x (y-stage + 2 delay lookups), run 4-layer MLP, k -> KDST.
#define DO_STAGE(ST, KPREV, KDST)                                                    \
    {                                                                                \
        const float cst = (ST == 0) ? 0.0f : ((ST == 1) ? 0.5f : 0.75f);             \
        if (act) {                                                                   \
            _Pragma("unroll") for (int t2 = 0; t2 < 2; ++t2) {                       \
                union { uint2 u; unsigned short s[4]; } p;                           \
                _Pragma("unroll") for (int j = 0; j < 4; ++j) {                      \
                    float yst = (ST == 0) ? y[t2][j]                                 \
                                          : fmaf(cst * dt, KPREV[t2][j], y[t2][j]);  \
                    p.s[j] = f2bf(yst);                                              \
                }                                                                    \
                *(uint2*)(xb + m * 256 + ((t2 * 32 + g * 8) ^ (m << 4))) = p.u;      \
            }                                                                        \
            const float tq = fmaf(cst, dt, t);                                       \
            _Pragma("unroll") for (int dl = 0; dl < 2; ++dl) {                       \
                float s = (tq - (dl ? 2.0f : 1.0f) - t0v) * ivd0;                    \
                s = fminf(fmaxf(s, 0.0f), 255.0f);                                   \
                const int   i0 = (int)s;                                             \
                const int   i1 = (i0 + 1 < TT - 1) ? i0 + 1 : TT - 1;                \
                const float w  = s - (float)i0;                                      \
                const int   s0 = i0 % WSLOTS, s1 = i1 % WSLOTS;                      \
                _Pragma("unroll") for (int t2 = 0; t2 < 2; ++t2) {                   \
                    const int ho = m * 72 + t2 * 32 + g * 8;                         \
                    uint2 a = *(const uint2*)((const char*)hist + s0 * 576 + ho);    \
                    uint2 b = *(const uint2*)((const char*)hist + s1 * 576 + ho);    \
                    union { uint2 u; unsigned short s[4]; } p;                       \
                    float v0, v1;                                                    \
                    v0 = bflo(a.x); v1 = bflo(b.x); p.s[0] = f2bf(fmaf(w, v1 - v0, v0)); \
                    v0 = bfhi(a.x); v1 = bfhi(b.x); p.s[1] = f2bf(fmaf(w, v1 - v0, v0)); \
                    v0 = bflo(a.y); v1 = bflo(b.y); p.s[2] = f2bf(fmaf(w, v1 - v0, v0)); \
                    v0 = bfhi(a.y); v1 = bfhi(b.y); p.s[3] = f2bf(fmaf(w, v1 - v0, v0)); \
                    *(uint2*)(xb + m * 256 + ((64 + dl * 64 + t2 * 32 + g * 8) ^ (m << 4))) = p.u; \
                }                                                                    \
            }                                                                        \
        }                                                                            \
        HID_LAYER(W0f[nt][kc], 3, xb, hA, 0)                                         \
        HID_LAYER(W1f[nt][kc], 4, hA, hB, 128)                                       \
        HID_LAYER(ldx(W2s, nt * 16 + m, kc * 64 + g * 16), 4, hB, hA, 256)           \
        {                                                                            \
            bf16x8 xf[4];                                                            \
            _Pragma("unroll") for (int kc = 0; kc < 4; ++kc)                         \
                xf[kc] = ldx(hA, r8, kc * 64 + g * 16);                              \
            _Pragma("unroll") for (int t2 = 0; t2 < 2; ++t2) {                       \
                f32x4 acc = *(const f32x4*)(biasb + 384 + t2 * 16 + g * 4);          \
                _Pragma("unroll") for (int kc = 0; kc < 4; ++kc)                     \
                    acc = __builtin_amdgcn_mfma_f32_16x16x32_bf16(W3f[t2][kc], xf[kc], acc, 0, 0, 0); \
                KDST[t2][0] = acc[0]; KDST[t2][1] = acc[1];                          \
                KDST[t2][2] = acc[2]; KDST[t2][3] = acc[3];                          \
            }                                                                        \
        }                                                                            \
    }

__global__ __launch_bounds__(64, 1) void dde_1w(
    const float* __restrict__ ts, const float* __restrict__ y0,
    const float* __restrict__ W0, const float* __restrict__ b0,
    const float* __restrict__ W1, const float* __restrict__ b1,
    const float* __restrict__ W2, const float* __restrict__ b2,
    const float* __restrict__ W3, const float* __restrict__ b3,
    float* __restrict__ out)
{
    __shared__ __align__(16) char W2s[128 * 256];                // 32 KB
    __shared__ __align__(16) unsigned short hist[WSLOTS][8][36]; // 29952 B, 72-B rows
    __shared__ __align__(16) char xb[8 * 256];                   // 2 KB (rows 0..7)
    __shared__ __align__(16) char hA[16 * 256];                  // 4 KB (rows 8..15 dup junk)
    __shared__ __align__(16) char hB[16 * 256];
    __shared__ __align__(16) float biasb[416];
    __shared__ float tsb[TT];

    const int  lane = threadIdx.x;
    const int  m    = lane & 15;
    const int  g    = lane >> 4;
    const int  r8   = m & 7;
    const int  R0   = blockIdx.x * 8;
    const bool act  = (m < 8);

    // ---- stage W2 -> LDS (bf16, swizzled) ----
    for (int grp = lane; grp < 128 * 16; grp += 64) {
        const int o  = grp >> 4;
        const int k8 = grp & 15;
        const float* s = W2 + o * 128 + k8 * 8;
        union { uint4 q; unsigned short h[8]; } t;
        #pragma unroll
        for (int j = 0; j < 8; ++j) t.h[j] = f2bf(s[j]);
        *(uint4*)(W2s + o * 256 + ((k8 * 16) ^ ((o & 7) << 4))) = t.q;
    }
    for (int idx = lane; idx < 416; idx += 64) {
        float v;
        if      (idx < 128) v = b0[idx];
        else if (idx < 256) v = b1[idx - 128];
        else if (idx < 384) v = b2[idx - 256];
        else                v = b3[idx - 384];
        biasb[idx] = v;
    }
    for (int idx = lane; idx < TT; idx += 64) tsb[idx] = ts[idx];
    for (int idx = lane; idx < WSLOTS * 8 * 36 / 2; idx += 64) ((unsigned*)hist)[idx] = 0u;

    // ---- register-resident weight fragments (W0, W1, W3) ----
    bf16x8 W0f[8][3], W1f[8][4], W3f[2][4];
    #pragma unroll
    for (int nt = 0; nt < 8; ++nt) {
        #pragma unroll
        for (int kc = 0; kc < 3; ++kc)
            W0f[nt][kc] = ldw8(W0 + (nt * 16 + m) * 96 + kc * 32 + g * 8);
        #pragma unroll
        for (int kc = 0; kc < 4; ++kc)
            W1f[nt][kc] = ldw8(W1 + (nt * 16 + m) * 128 + kc * 32 + g * 8);
    }
    #pragma unroll
    for (int t2 = 0; t2 < 2; ++t2)
        #pragma unroll
        for (int kc = 0; kc < 4; ++kc)
            W3f[t2][kc] = ldw8(W3 + (t2 * 16 + m) * 128 + kc * 32 + g * 8);

    // ---- init y, hist[0], out[0] ----
    float y[2][4], k1[2][4], k2[2][4], k3[2][4];
    if (act) {
        #pragma unroll
        for (int t2 = 0; t2 < 2; ++t2) {
            float4 v = *(const float4*)(y0 + (R0 + m) * DATA + t2 * 16 + g * 4);
            y[t2][0] = v.x; y[t2][1] = v.y; y[t2][2] = v.z; y[t2][3] = v.w;
            union { uint2 u; unsigned short s[4]; } p;
            p.s[0] = f2bf(v.x); p.s[1] = f2bf(v.y); p.s[2] = f2bf(v.z); p.s[3] = f2bf(v.w);
            *(uint2*)((char*)hist + m * 72 + t2 * 32 + g * 8) = p.u;
            *(float4*)(out + (R0 + m) * DATA + t2 * 16 + g * 4) = v;
        }
    }
    if (blockIdx.x == 0 && lane == 0)
        out[(size_t)TT * BATCH * DATA] = 255.0f;   // second tuple output: int32(T-1)

    const float t0v  = tsb[0];
    const float ivd0 = 1.0f / (tsb[1] - tsb[0]);

    #pragma unroll 1
    for (int i = 0; i < TT - 1; ++i) {
        const float t  = tsb[i];
        const float dt = tsb[i + 1] - t;

        DO_STAGE(0, k1, k1)
        DO_STAGE(1, k1, k2)
        DO_STAGE(2, k2, k3)

        if (act) {
            const int ws = (i + 1) % WSLOTS;
            #pragma unroll
            for (int t2 = 0; t2 < 2; ++t2) {
                union { uint2 u; unsigned short s[4]; } p;
                float4 v;
                #pragma unroll
                for (int j = 0; j < 4; ++j) {
                    const float ks = (2.0f / 9.0f) * k1[t2][j] + (1.0f / 3.0f) * k2[t2][j]
                                   + (4.0f / 9.0f) * k3[t2][j];
                    y[t2][j] = fmaf(dt, ks, y[t2][j]);
                }
                v.x = y[t2][0]; v.y = y[t2][1]; v.z = y[t2][2]; v.w = y[t2][3];
                p.s[0] = f2bf(v.x); p.s[1] = f2bf(v.y); p.s[2] = f2bf(v.z); p.s[3] = f2bf(v.w);
                *(uint2*)((char*)hist + ws * 576 + m * 72 + t2 * 32 + g * 8) = p.u;
                *(float4*)(out + (size_t)(i + 1) * BATCH * DATA + (R0 + m) * DATA
                           + t2 * 16 + g * 4) = v;
            }
        }
    }
}

extern "C" void kernel_launch(void* const* d_in, const int* in_sizes, int n_in,
                              void* d_out, int out_size, void* d_ws, size_t ws_size,
                              hipStream_t stream) {
    const float* ts = (const float*)d_in[0];
    const float* y0 = (const float*)d_in[1];
    const float* W0 = (const float*)d_in[2];
    const float* b0 = (const float*)d_in[3];
    const float* W1 = (const float*)d_in[4];
    const float* b1 = (const float*)d_in[5];
    const float* W2 = (const float*)d_in[6];
    const float* b2 = (const float*)d_in[7];
    const float* W3 = (const float*)d_in[8];
    const float* b3 = (const float*)d_in[9];

    dde_1w<<<dim3(BATCH / 8), dim3(64), 0, stream>>>(
        ts, y0, W0, b0, W1, b1, W2, b2, W3, b3, (float*)d_out);
}

// Round 4
// 800.354 us; speedup vs baseline: 3.3183x; 3.3183x over previous
//
#include <hip/hip_runtime.h>

#define TT 256
#define BATCH 2048
#define DATA 32
#define WSLOTS 52

typedef __bf16 bf16x8 __attribute__((ext_vector_type(8)));
typedef float f32x4 __attribute__((ext_vector_type(4)));

union bfp2 { uint2 u; __bf16 b[4]; };

// fp32 x8 (global) -> bf16x8 fragment (prologue only)
__device__ __forceinline__ bf16x8 ldw8(const float* __restrict__ p) {
    float4 a = *(const float4*)p;
    float4 b = *(const float4*)(p + 4);
    bf16x8 r;
    r[0] = (__bf16)a.x; r[1] = (__bf16)a.y; r[2] = (__bf16)a.z; r[3] = (__bf16)a.w;
    r[4] = (__bf16)b.x; r[5] = (__bf16)b.y; r[6] = (__bf16)b.z; r[7] = (__bf16)b.w;
    return r;
}

// swizzled LDS fragment read: 256-B row stride, 16-B slot XOR (row&7)
__device__ __forceinline__ bf16x8 ldx(const char* base, int row, int kbyte) {
    return *(const bf16x8*)(base + row * 256 + (kbyte ^ ((row & 7) << 4)));
}

// Two 16-col output tiles (this wave's share of a 128-wide layer).
// A = weight frags (regs), B = activations (LDS). D: lane&15 = batch row m,
// (lane>>4)*4+j = col within tile -> 4 consecutive cols -> one b64 store/tile.
#define HID2(WF, KC, SRC, DST, BI0, BI1)                                              \
    {                                                                                 \
        bf16x8 xf[4];                                                                 \
        _Pragma("unroll") for (int kc = 0; kc < (KC); ++kc)                           \
            xf[kc] = ldx(SRC, m, kc * 64 + g * 16);                                   \
        f32x4 a0 = BI0, a1 = BI1;                                                     \
        _Pragma("unroll") for (int kc = 0; kc < (KC); ++kc) {                         \
            a0 = __builtin_amdgcn_mfma_f32_16x16x32_bf16(WF[0][kc], xf[kc], a0, 0, 0, 0); \
            a1 = __builtin_amdgcn_mfma_f32_16x16x32_bf16(WF[1][kc], xf[kc], a1, 0, 0, 0); \
        }                                                                             \
        bfp2 p0, p1;                                                                  \
        _Pragma("unroll") for (int j = 0; j < 4; ++j) {                               \
            p0.b[j] = (__bf16)fmaxf(a0[j], 0.0f);                                     \
            p1.b[j] = (__bf16)fmaxf(a1[j], 0.0f);                                     \
        }                                                                             \
        char* dr = (DST) + m * 256;                                                   \
        const int sw = (m & 7) << 4;                                                  \
        *(uint2*)(dr + ((tbB + g * 8) ^ sw)) = p0.u;                                  \
        *(uint2*)(dr + ((tbB + 32 + g * 8) ^ sw)) = p1.u;                             \
    }

// Assemble x = [y_stage | lerp(hist, tq-1) | lerp(hist, tq-2)] (waves 0/1; lane
// writes only its own 4 cols; hist cells are lane-private -> no cross-wave races)
#define ASSEMBLE(USEK, CST, KP)                                                       \
    if (wv < 2) {                                                                     \
        bfp2 py;                                                                      \
        _Pragma("unroll") for (int j = 0; j < 4; ++j)                                 \
            py.b[j] = (__bf16)((USEK) ? fmaf((CST) * dt, KP[j], y[j]) : y[j]);        \
        char* xr = xb + m * 256;                                                      \
        const int sw = (m & 7) << 4;                                                  \
        *(uint2*)(xr + (cb2 ^ sw)) = py.u;                                            \
        const float tq = fmaf((CST), dt, t);                                          \
        _Pragma("unroll") for (int dl = 0; dl < 2; ++dl) {                            \
            float s = (tq - (dl ? 2.0f : 1.0f) - t0v) * ivd0;                         \
            s = fminf(fmaxf(s, 0.0f), 255.0f);                                        \
            const int   i0 = (int)s;                                                  \
            const int   i1 = (i0 + 1 < TT - 1) ? i0 + 1 : TT - 1;                     \
            const float w  = s - (float)i0;                                           \
            bfp2 pa, pb, pr;                                                          \
            pa.u = *(const uint2*)(histc + (i0 % WSLOTS) * 1152 + m * 72 + cb2);      \
            pb.u = *(const uint2*)(histc + (i1 % WSLOTS) * 1152 + m * 72 + cb2);      \
            _Pragma("unroll") for (int j = 0; j < 4; ++j) {                           \
                const float va = (float)pa.b[j], vb = (float)pb.b[j];                 \
                pr.b[j] = (__bf16)fmaf(w, vb - va, va);                               \
            }                                                                         \
            *(uint2*)(xr + ((64 + dl * 64 + cb2) ^ sw)) = pr.u;                       \
        }                                                                             \
    }

#define DO_STAGE(USEK, CST, KP, KD)                                                   \
    ASSEMBLE(USEK, CST, KP)                                                           \
    __syncthreads();                                                                  \
    HID2(W0f, 3, xb, hA, bias0[0], bias0[1])                                          \
    __syncthreads();                                                                  \
    HID2(W1f, 4, hA, hB, bias1[0], bias1[1])                                          \
    __syncthreads();                                                                  \
    HID2(W2f, 4, hB, hA, bias2[0], bias2[1])                                          \
    __syncthreads();                                                                  \
    if (wv < 2) {                                                                     \
        bf16x8 xf[4];                                                                 \
        _Pragma("unroll") for (int kc = 0; kc < 4; ++kc)                              \
            xf[kc] = ldx(hA, m, kc * 64 + g * 16);                                    \
        f32x4 a = bias3;                                                              \
        _Pragma("unroll") for (int kc = 0; kc < 4; ++kc)                              \
            a = __builtin_amdgcn_mfma_f32_16x16x32_bf16(W3f[kc], xf[kc], a, 0, 0, 0); \
        KD = a;                                                                       \
    }

__global__ __launch_bounds__(256, 1) void dde_4w(
    const float* __restrict__ ts, const float* __restrict__ y0,
    const float* __restrict__ W0, const float* __restrict__ b0,
    const float* __restrict__ W1, const float* __restrict__ b1,
    const float* __restrict__ W2, const float* __restrict__ b2,
    const float* __restrict__ W3, const float* __restrict__ b3,
    float* __restrict__ out)
{
    __shared__ __align__(16) unsigned short hist[WSLOTS][16][36]; // 59904 B, 72-B rows
    __shared__ __align__(16) char xb[16 * 256];
    __shared__ __align__(16) char hA[16 * 256];
    __shared__ __align__(16) char hB[16 * 256];
    __shared__ float tsb[TT];
    // ~73 KB LDS

    const int tid  = threadIdx.x;
    const int lane = tid & 63;
    const int wv   = tid >> 6;        // wave 0..3
    const int m    = lane & 15;       // batch row within block
    const int g    = lane >> 4;       // k-group / col-quad
    const int tbB  = wv * 64;         // byte base of this wave's first hidden tile
    const int cb   = wv * 16 + g * 4; // owned output cols (waves 0/1 only)
    const int cb2  = cb * 2;
    const int R0   = blockIdx.x * 16;
    char* histc = (char*)hist;

    for (int idx = tid; idx < WSLOTS * 16 * 18; idx += 256) ((unsigned*)hist)[idx] = 0u;
    for (int idx = tid; idx < TT; idx += 256) tsb[idx] = ts[idx];

    // ---- register-resident weight fragments: 26 frags = 104 VGPR ----
    bf16x8 W0f[2][3], W1f[2][4], W2f[2][4], W3f[4];
    #pragma unroll
    for (int ti = 0; ti < 2; ++ti) {
        const int rw = (wv * 2 + ti) * 16 + m;
        #pragma unroll
        for (int kc = 0; kc < 3; ++kc) W0f[ti][kc] = ldw8(W0 + rw * 96 + kc * 32 + g * 8);
        #pragma unroll
        for (int kc = 0; kc < 4; ++kc) W1f[ti][kc] = ldw8(W1 + rw * 128 + kc * 32 + g * 8);
        #pragma unroll
        for (int kc = 0; kc < 4; ++kc) W2f[ti][kc] = ldw8(W2 + rw * 128 + kc * 32 + g * 8);
    }
    {
        const int rw3 = (wv & 1) * 16 + m;     // masked row keeps waves 2/3 in-bounds
        #pragma unroll
        for (int kc = 0; kc < 4; ++kc) W3f[kc] = ldw8(W3 + rw3 * 128 + kc * 32 + g * 8);
    }
    f32x4 bias0[2], bias1[2], bias2[2], bias3;
    #pragma unroll
    for (int ti = 0; ti < 2; ++ti) {
        bias0[ti] = *(const f32x4*)(b0 + (wv * 2 + ti) * 16 + g * 4);
        bias1[ti] = *(const f32x4*)(b1 + (wv * 2 + ti) * 16 + g * 4);
        bias2[ti] = *(const f32x4*)(b2 + (wv * 2 + ti) * 16 + g * 4);
    }
    bias3 = *(const f32x4*)(b3 + (wv & 1) * 16 + g * 4);

    __syncthreads();   // hist zero complete before slot-0 init

    f32x4 y = {0.f, 0.f, 0.f, 0.f}, k1 = y, k2 = y, k3 = y;
    if (wv < 2) {
        float4 v = *(const float4*)(y0 + (R0 + m) * DATA + cb);
        y[0] = v.x; y[1] = v.y; y[2] = v.z; y[3] = v.w;
        bfp2 p;
        #pragma unroll
        for (int j = 0; j < 4; ++j) p.b[j] = (__bf16)y[j];
        *(uint2*)(histc + m * 72 + cb2) = p.u;            // hist slot 0 = y0
        *(float4*)(out + (R0 + m) * DATA + cb) = v;       // ys[0] = y0 exact
    }
    if (blockIdx.x == 0 && tid == 0)
        out[(size_t)TT * BATCH * DATA] = 255.0f;          // tuple output 1: int32(T-1)
    __syncthreads();

    const float t0v  = tsb[0];
    const float ivd0 = 1.0f / (tsb[1] - tsb[0]);

    #pragma unroll 1
    for (int i = 0; i < TT - 1; ++i) {
        const float t  = tsb[i];
        const float dt = tsb[i + 1] - t;

        DO_STAGE(0, 0.0f,  k1, k1)
        DO_STAGE(1, 0.5f,  k1, k2)
        DO_STAGE(2, 0.75f, k2, k3)

        if (wv < 2) {
            #pragma unroll
            for (int j = 0; j < 4; ++j) {
                const float ks = (2.0f / 9.0f) * k1[j] + (1.0f / 3.0f) * k2[j]
                               + (4.0f / 9.0f) * k3[j];
                y[j] = fmaf(dt, ks, y[j]);
            }
            bfp2 p; float4 v;
            p.b[0] = (__bf16)y[0]; p.b[1] = (__bf16)y[1];
            p.b[2] = (__bf16)y[2]; p.b[3] = (__bf16)y[3];
            v.x = y[0]; v.y = y[1]; v.z = y[2]; v.w = y[3];
            *(uint2*)(histc + ((i + 1) % WSLOTS) * 1152 + m * 72 + cb2) = p.u;
            *(float4*)(out + (size_t)(i + 1) * BATCH * DATA + (R0 + m) * DATA + cb) = v;
        }
        // hist/xb hazards: lane-private cells (same-wave in-order); cross-wave
        // xb/h handoffs are fenced by the 4 in-stage barriers.
    }
}

extern "C" void kernel_launch(void* const* d_in, const int* in_sizes, int n_in,
                              void* d_out, int out_size, void* d_ws, size_t ws_size,
                              hipStream_t stream) {
    const float* ts = (const float*)d_in[0];
    const float* y0 = (const float*)d_in[1];
    const float* W0 = (const float*)d_in[2];
    const float* b0 = (const float*)d_in[3];
    const float* W1 = (const float*)d_in[4];
    const float* b1 = (const float*)d_in[5];
    const float* W2 = (const float*)d_in[6];
    const float* b2 = (const float*)d_in[7];
    const float* W3 = (const float*)d_in[8];
    const float* b3 = (const float*)d_in[9];

    dde_4w<<<dim3(BATCH / 16), dim3(256), 0, stream>>>(
        ts, y0, W0, b0, W1, b1, W2, b2, W3, b3, (float*)d_out);
}